// Round 7
// baseline (2701.312 us; speedup 1.0000x reference)
//
#include <hip/hip_runtime.h>
#include <hip/hip_bf16.h>

#define NMAX   100000
#define NGRAPH 256
#define DIN    192
#define HDIM   64
#define DOUTD  32
#define NCLS   2

// All scratch in device globals — no dependence on d_ws / ws_size.
__device__ int   g_deg[NMAX];
__device__ float g_dis[NMAX];
__device__ float g_h[NMAX * HDIM];     // layer activations
__device__ float g_t[NMAX * HDIM];     // h @ W (pre-aggregation), ref order
__device__ float g_agg[NMAX * HDIM];   // normalized-adjacency aggregation
__device__ float g_gsum[NGRAPH * HDIM];
__device__ float g_gcnt[NGRAPH];
__device__ int   g_cc;
__device__ int   g_flag;               // 0 = (2,E) contiguous, 1 = (E,2) interleaved

__device__ __forceinline__ void load_edge(const int* __restrict__ ei, int E, int e,
                                          int& s, int& d) {
    if (g_flag) { s = ei[2 * e]; d = ei[2 * e + 1]; }
    else        { s = ei[e];     d = ei[e + E];     }
}

__global__ void k_prep(int n) {
    int i = blockIdx.x * blockDim.x + threadIdx.x;
    if (i == 0) g_cc = 0;
    if (i < n) g_deg[i] = 0;
    if (i < NGRAPH * HDIM) g_gsum[i] = 0.0f;
    if (i < NGRAPH) g_gcnt[i] = 0.0f;
}

// layout detection: contiguous reading of a true (2,E) edge list gives zero
// src==dst collisions (reference guarantees no self-loops)
__global__ void k_detect(const int* __restrict__ ei, int E) {
    int e = blockIdx.x * blockDim.x + threadIdx.x;
    if (e < E && ei[e] == ei[e + E]) atomicAdd(&g_cc, 1);
}

__global__ void k_setflag() { g_flag = (g_cc != 0) ? 1 : 0; }

__global__ void k_deg(const int* __restrict__ ei, int E) {
    int e = blockIdx.x * blockDim.x + threadIdx.x;
    if (e < E) {
        int s, d;
        load_edge(ei, E, e, s, d);
        atomicAdd(&g_deg[s], 1);
        atomicAdd(&g_deg[d], 1);
    }
}

__global__ void k_dis(int n) {
    int i = blockIdx.x * blockDim.x + threadIdx.x;
    if (i < n) g_dis[i] = 1.0f / sqrtf((float)g_deg[i] + 1.0f);
}

// h = relu(x @ W_in + b_in); all fp32
__global__ void k_in(const float* __restrict__ x,
                     const float* __restrict__ W,
                     const float* __restrict__ b, int n) {
    int idx  = blockIdx.x * blockDim.x + threadIdx.x;
    int node = idx >> 6;
    int f    = idx & 63;
    if (node >= n) return;
    float acc = b[f];
    const float* xr = x + (long long)node * DIN;
    for (int k = 0; k < DIN; ++k)
        acc += xr[k] * W[k * HDIM + f];
    g_h[node * HDIM + f] = fmaxf(acc, 0.0f);
}

// t = h @ W  (reference order: HW first, then aggregate)
__global__ void k_hw(const float* __restrict__ W, int n) {
    int idx  = blockIdx.x * blockDim.x + threadIdx.x;
    int node = idx >> 6;
    int f    = idx & 63;
    if (node >= n) return;
    float acc = 0.0f;
    const float* hr = g_h + node * HDIM;
    for (int k = 0; k < HDIM; ++k)
        acc += hr[k] * W[k * HDIM + f];
    g_t[node * HDIM + f] = acc;
}

// agg := t * dis^2  (self-loop term; serves as the zero-init)
__global__ void k_agginit(int n) {
    int idx  = blockIdx.x * blockDim.x + threadIdx.x;
    int node = idx >> 6;
    int f    = idx & 63;
    if (node >= n) return;
    float di = g_dis[node];
    g_agg[node * HDIM + f] = g_t[node * HDIM + f] * di * di;
}

// message passing: one lane per (edge, feature); both undirected directions
__global__ void k_edge(const int* __restrict__ ei, int E) {
    long long idx = (long long)blockIdx.x * blockDim.x + threadIdx.x;
    int e = (int)(idx >> 6);
    int f = (int)(idx & 63);
    if (e >= E) return;
    int s, d;
    load_edge(ei, E, e, s, d);
    float c = g_dis[s] * g_dis[d];
    atomicAdd(&g_agg[d * HDIM + f], g_t[s * HDIM + f] * c);
    atomicAdd(&g_agg[s * HDIM + f], g_t[d * HDIM + f] * c);
}

// h := relu(agg + b)
__global__ void k_self(const float* __restrict__ b, int n) {
    int idx  = blockIdx.x * blockDim.x + threadIdx.x;
    int node = idx >> 6;
    int f    = idx & 63;
    if (node >= n) return;
    g_h[node * HDIM + f] = fmaxf(g_agg[node * HDIM + f] + b[f], 0.0f);
}

// global mean-pool accumulation
__global__ void k_pool(const int* __restrict__ batch, int n) {
    int idx  = blockIdx.x * blockDim.x + threadIdx.x;
    int node = idx >> 6;
    int f    = idx & 63;
    if (node >= n) return;
    int g = batch[node];
    atomicAdd(&g_gsum[g * HDIM + f], g_h[node * HDIM + f]);
    if (f == 0) atomicAdd(&g_gcnt[g], 1.0f);
}

// per-graph MLP head + log_softmax; fp32 throughout
__global__ void k_head(const float* __restrict__ Wf1, const float* __restrict__ bf1,
                       const float* __restrict__ Wf2, const float* __restrict__ bf2,
                       float* __restrict__ out) {
    __shared__ float p[HDIM];
    __shared__ float z[DOUTD];
    int g = blockIdx.x;
    int t = threadIdx.x;
    float cnt = fmaxf(g_gcnt[g], 1.0f);
    p[t] = g_gsum[g * HDIM + t] / cnt;
    __syncthreads();
    if (t < DOUTD) {
        float a = bf1[t];
        for (int k = 0; k < HDIM; ++k)
            a += p[k] * Wf1[k * DOUTD + t];
        z[t] = fmaxf(a, 0.0f);
    }
    __syncthreads();
    if (t == 0) {
        float l0 = bf2[0], l1 = bf2[1];
        for (int k = 0; k < DOUTD; ++k) {
            l0 += z[k] * Wf2[k * NCLS + 0];
            l1 += z[k] * Wf2[k * NCLS + 1];
        }
        float m   = fmaxf(l0, l1);
        float lse = m + logf(expf(l0 - m) + expf(l1 - m));
        out[g * NCLS + 0] = l0 - lse;
        out[g * NCLS + 1] = l1 - lse;
    }
}

extern "C" void kernel_launch(void* const* d_in, const int* in_sizes, int n_in,
                              void* d_out, int out_size, void* d_ws, size_t ws_size,
                              hipStream_t stream) {
    (void)d_ws; (void)ws_size; (void)out_size;

    const float* x   = (const float*)d_in[0];   // fp32 per reference setup
    const int*   ei  = (const int*)d_in[1];
    const int*   bat = (const int*)d_in[2];

    // by-size binding: skip scalar entries (num_graphs) after index 2
    const float* wp[10] = {nullptr};
    int wi = 0;
    for (int i = 3; i < n_in && wi < 10; ++i) {
        if (in_sizes[i] == 1) continue;
        wp[wi++] = (const float*)d_in[i];
    }
    const float* W_in = wp[0];
    const float* b_in = wp[1];
    const float* W1   = wp[2];
    const float* b1   = wp[3];
    const float* W2   = wp[4];
    const float* b2   = wp[5];
    const float* Wf1  = wp[6];
    const float* bf1  = wp[7];
    const float* Wf2  = wp[8];
    const float* bf2  = wp[9];

    const int n = in_sizes[0] / DIN;  // N nodes
    const int E = in_sizes[1] / 2;    // directed edges

    const int B = 256;
    int gE  = (E + B - 1) / B;
    int gN  = (n + B - 1) / B;
    int gNH = (int)(((long long)n * HDIM + B - 1) / B);
    int gEH = (int)(((long long)E * HDIM + B - 1) / B);

    k_prep<<<gN, B, 0, stream>>>(n);
    k_detect<<<gE, B, 0, stream>>>(ei, E);
    k_setflag<<<1, 1, 0, stream>>>();
    k_deg<<<gE, B, 0, stream>>>(ei, E);
    k_dis<<<gN, B, 0, stream>>>(n);

    k_in<<<gNH, B, 0, stream>>>(x, W_in, b_in, n);

    // conv 1
    k_hw<<<gNH, B, 0, stream>>>(W1, n);
    k_agginit<<<gNH, B, 0, stream>>>(n);
    k_edge<<<gEH, B, 0, stream>>>(ei, E);
    k_self<<<gNH, B, 0, stream>>>(b1, n);

    // conv 2
    k_hw<<<gNH, B, 0, stream>>>(W2, n);
    k_agginit<<<gNH, B, 0, stream>>>(n);
    k_edge<<<gEH, B, 0, stream>>>(ei, E);
    k_self<<<gNH, B, 0, stream>>>(b2, n);

    // pooling + head
    k_pool<<<gNH, B, 0, stream>>>(bat, n);
    k_head<<<NGRAPH, 64, 0, stream>>>(Wf1, bf1, Wf2, bf2, (float*)d_out);
}

// Round 8
// 1944.359 us; speedup vs baseline: 1.3893x; 1.3893x over previous
//
#include <hip/hip_runtime.h>
#include <hip/hip_bf16.h>

#define NMAX   100000
#define EMAX   1600000
#define NGRAPH 256
#define DIN    192
#define HDIM   64
#define DOUTD  32
#define NCLS   2
#define SCAN_B 512

// All scratch in device globals — no dependence on d_ws / ws_size.
__device__ int   g_deg[NMAX];
__device__ float g_dis[NMAX];
__device__ float g_h[NMAX * HDIM];       // layer activations
__device__ float g_t[NMAX * HDIM];       // h @ W (pre-aggregation)
__device__ float g_gsum[NGRAPH * HDIM];
__device__ float g_gcnt[NGRAPH];
__device__ int   g_row[NMAX + 1];        // CSR row pointers
__device__ int   g_cur[NMAX];            // fill cursors
__device__ int   g_col[2 * EMAX];        // CSR neighbor lists (both directions)
__device__ int   g_bsum[256];            // scan block sums
__device__ int   g_boff[256];            // scan block offsets
__device__ int   g_cc;
__device__ int   g_flag;                 // 0 = (2,E) contiguous, 1 = (E,2) interleaved

__device__ __forceinline__ void load_edge(const int* __restrict__ ei, int E, int e,
                                          int& s, int& d) {
    if (g_flag) { s = ei[2 * e]; d = ei[2 * e + 1]; }
    else        { s = ei[e];     d = ei[e + E];     }
}

__global__ void k_prep(int n) {
    int i = blockIdx.x * blockDim.x + threadIdx.x;
    if (i == 0) g_cc = 0;
    if (i < n) g_deg[i] = 0;
    if (i < NGRAPH * HDIM) g_gsum[i] = 0.0f;
    if (i < NGRAPH) g_gcnt[i] = 0.0f;
}

// layout detection: contiguous reading of a true (2,E) edge list gives zero
// src==dst collisions (reference guarantees no self-loops)
__global__ void k_detect(const int* __restrict__ ei, int E) {
    int e = blockIdx.x * blockDim.x + threadIdx.x;
    if (e < E && ei[e] == ei[e + E]) atomicAdd(&g_cc, 1);
}

__global__ void k_setflag() { g_flag = (g_cc != 0) ? 1 : 0; }

__global__ void k_deg(const int* __restrict__ ei, int E) {
    int e = blockIdx.x * blockDim.x + threadIdx.x;
    if (e < E) {
        int s, d;
        load_edge(ei, E, e, s, d);
        atomicAdd(&g_deg[s], 1);
        atomicAdd(&g_deg[d], 1);
    }
}

__global__ void k_dis(int n) {
    int i = blockIdx.x * blockDim.x + threadIdx.x;
    if (i < n) g_dis[i] = 1.0f / sqrtf((float)g_deg[i] + 1.0f);
}

// ---- CSR construction: inclusive scan of deg -> g_row[1..n], g_row[0]=0 ----
__global__ void k_scan1(int n) {
    __shared__ int sh[SCAN_B];
    int i = blockIdx.x * SCAN_B + threadIdx.x;
    sh[threadIdx.x] = (i < n) ? g_deg[i] : 0;
    __syncthreads();
    for (int off = 1; off < SCAN_B; off <<= 1) {
        int t = (threadIdx.x >= off) ? sh[threadIdx.x - off] : 0;
        __syncthreads();
        sh[threadIdx.x] += t;
        __syncthreads();
    }
    if (i < n) g_row[i + 1] = sh[threadIdx.x];       // pre-offset inclusive
    if (threadIdx.x == SCAN_B - 1) g_bsum[blockIdx.x] = sh[SCAN_B - 1];
}

__global__ void k_scan2(int nb) {
    if (threadIdx.x == 0 && blockIdx.x == 0) {
        int acc = 0;
        for (int b = 0; b < nb; ++b) { g_boff[b] = acc; acc += g_bsum[b]; }
    }
}

__global__ void k_scan3(int n) {
    int i = blockIdx.x * SCAN_B + threadIdx.x;
    if (i < n) g_row[i + 1] += g_boff[blockIdx.x];
    if (i == 0) g_row[0] = 0;
}

__global__ void k_cur(int n) {
    int i = blockIdx.x * blockDim.x + threadIdx.x;
    if (i < n) g_cur[i] = g_row[i];
}

__global__ void k_fill(const int* __restrict__ ei, int E) {
    int e = blockIdx.x * blockDim.x + threadIdx.x;
    if (e >= E) return;
    int s, d;
    load_edge(ei, E, e, s, d);
    int p = atomicAdd(&g_cur[d], 1); g_col[p] = s;
    int q = atomicAdd(&g_cur[s], 1); g_col[q] = d;
}

// ---- dense layers ----
// h = relu(x @ W_in + b_in); all fp32
__global__ void k_in(const float* __restrict__ x,
                     const float* __restrict__ W,
                     const float* __restrict__ b, int n) {
    int idx  = blockIdx.x * blockDim.x + threadIdx.x;
    int node = idx >> 6;
    int f    = idx & 63;
    if (node >= n) return;
    float acc = b[f];
    const float* xr = x + (long long)node * DIN;
    for (int k = 0; k < DIN; ++k)
        acc += xr[k] * W[k * HDIM + f];
    g_h[node * HDIM + f] = fmaxf(acc, 0.0f);
}

// t = h @ W  (reference order: HW first, then aggregate)
__global__ void k_hw(const float* __restrict__ W, int n) {
    int idx  = blockIdx.x * blockDim.x + threadIdx.x;
    int node = idx >> 6;
    int f    = idx & 63;
    if (node >= n) return;
    float acc = 0.0f;
    const float* hr = g_h + node * HDIM;
    for (int k = 0; k < HDIM; ++k)
        acc += hr[k] * W[k * HDIM + f];
    g_t[node * HDIM + f] = acc;
}

// CSR gather aggregation fused with self-loop + bias + relu:
// h_v = relu( dis_v * sum_u dis_u * t_u  +  dis_v^2 * t_v  +  b )
// one wave (64 lanes = 64 features) per node -> degree loop is wave-uniform
__global__ void k_gather(const float* __restrict__ b, int n) {
    int idx = blockIdx.x * blockDim.x + threadIdx.x;
    int v   = idx >> 6;
    int f   = idx & 63;
    if (v >= n) return;
    int beg = g_row[v], end = g_row[v + 1];
    float acc = 0.0f;
    for (int j = beg; j < end; ++j) {
        int u = g_col[j];
        acc += g_dis[u] * g_t[(size_t)u * HDIM + f];
    }
    float dv = g_dis[v];
    float r  = dv * acc + dv * dv * g_t[(size_t)v * HDIM + f] + b[f];
    g_h[(size_t)v * HDIM + f] = fmaxf(r, 0.0f);
}

// global mean-pool accumulation
__global__ void k_pool(const int* __restrict__ batch, int n) {
    int idx  = blockIdx.x * blockDim.x + threadIdx.x;
    int node = idx >> 6;
    int f    = idx & 63;
    if (node >= n) return;
    int g = batch[node];
    atomicAdd(&g_gsum[g * HDIM + f], g_h[node * HDIM + f]);
    if (f == 0) atomicAdd(&g_gcnt[g], 1.0f);
}

// per-graph MLP head + log_softmax; fp32 throughout
__global__ void k_head(const float* __restrict__ Wf1, const float* __restrict__ bf1,
                       const float* __restrict__ Wf2, const float* __restrict__ bf2,
                       float* __restrict__ out) {
    __shared__ float p[HDIM];
    __shared__ float z[DOUTD];
    int g = blockIdx.x;
    int t = threadIdx.x;
    float cnt = fmaxf(g_gcnt[g], 1.0f);
    p[t] = g_gsum[g * HDIM + t] / cnt;
    __syncthreads();
    if (t < DOUTD) {
        float a = bf1[t];
        for (int k = 0; k < HDIM; ++k)
            a += p[k] * Wf1[k * DOUTD + t];
        z[t] = fmaxf(a, 0.0f);
    }
    __syncthreads();
    if (t == 0) {
        float l0 = bf2[0], l1 = bf2[1];
        for (int k = 0; k < DOUTD; ++k) {
            l0 += z[k] * Wf2[k * NCLS + 0];
            l1 += z[k] * Wf2[k * NCLS + 1];
        }
        float m   = fmaxf(l0, l1);
        float lse = m + logf(expf(l0 - m) + expf(l1 - m));
        out[g * NCLS + 0] = l0 - lse;
        out[g * NCLS + 1] = l1 - lse;
    }
}

extern "C" void kernel_launch(void* const* d_in, const int* in_sizes, int n_in,
                              void* d_out, int out_size, void* d_ws, size_t ws_size,
                              hipStream_t stream) {
    (void)d_ws; (void)ws_size; (void)out_size;

    const float* x   = (const float*)d_in[0];   // fp32 per reference setup
    const int*   ei  = (const int*)d_in[1];
    const int*   bat = (const int*)d_in[2];

    // by-size binding: skip scalar entries (num_graphs) after index 2
    const float* wp[10] = {nullptr};
    int wi = 0;
    for (int i = 3; i < n_in && wi < 10; ++i) {
        if (in_sizes[i] == 1) continue;
        wp[wi++] = (const float*)d_in[i];
    }
    const float* W_in = wp[0];
    const float* b_in = wp[1];
    const float* W1   = wp[2];
    const float* b1   = wp[3];
    const float* W2   = wp[4];
    const float* b2   = wp[5];
    const float* Wf1  = wp[6];
    const float* bf1  = wp[7];
    const float* Wf2  = wp[8];
    const float* bf2  = wp[9];

    const int n = in_sizes[0] / DIN;  // N nodes
    const int E = in_sizes[1] / 2;    // directed edges

    const int B = 256;
    int gE  = (E + B - 1) / B;
    int gN  = (n + B - 1) / B;
    int gNH = (int)(((long long)n * HDIM + B - 1) / B);
    int nb  = (n + SCAN_B - 1) / SCAN_B;   // scan blocks (196 for N=100K)

    // degree + dis
    k_prep<<<gN, B, 0, stream>>>(n);
    k_detect<<<gE, B, 0, stream>>>(ei, E);
    k_setflag<<<1, 1, 0, stream>>>();
    k_deg<<<gE, B, 0, stream>>>(ei, E);
    k_dis<<<gN, B, 0, stream>>>(n);

    // CSR build
    k_scan1<<<nb, SCAN_B, 0, stream>>>(n);
    k_scan2<<<1, 1, 0, stream>>>(nb);
    k_scan3<<<nb, SCAN_B, 0, stream>>>(n);
    k_cur<<<gN, B, 0, stream>>>(n);
    k_fill<<<gE, B, 0, stream>>>(ei, E);

    // input layer
    k_in<<<gNH, B, 0, stream>>>(x, W_in, b_in, n);

    // conv 1
    k_hw<<<gNH, B, 0, stream>>>(W1, n);
    k_gather<<<gNH, B, 0, stream>>>(b1, n);

    // conv 2
    k_hw<<<gNH, B, 0, stream>>>(W2, n);
    k_gather<<<gNH, B, 0, stream>>>(b2, n);

    // pooling + head
    k_pool<<<gNH, B, 0, stream>>>(bat, n);
    k_head<<<NGRAPH, 64, 0, stream>>>(Wf1, bf1, Wf2, bf2, (float*)d_out);
}

// Round 9
// 1731.341 us; speedup vs baseline: 1.5602x; 1.1230x over previous
//
#include <hip/hip_runtime.h>
#include <hip/hip_bf16.h>

#define NMAX   100000
#define EMAX   1600000
#define NGRAPH 256
#define DIN    192
#define HDIM   64
#define DOUTD  32
#define NCLS   2
#define SCAN_B 512

// All scratch in device globals — no dependence on d_ws / ws_size.
__device__ int   g_deg[NMAX];
__device__ float g_dis[NMAX];
__device__ float g_h[NMAX * HDIM];       // layer activations
__device__ float g_t[NMAX * HDIM];       // h @ W (pre-aggregation)
__device__ int   g_row[NMAX + 1];        // CSR row pointers
__device__ int   g_cur[NMAX];            // fill cursors
__device__ int   g_col[2 * EMAX];        // CSR neighbor lists (both directions)
__device__ int   g_gptr[NGRAPH + 1];     // per-graph node ranges (batch is sorted)
__device__ int   g_bsum[256];            // scan block sums
__device__ int   g_boff[256];            // scan block offsets
__device__ int   g_cc;
__device__ int   g_flag;                 // 0 = (2,E) contiguous, 1 = (E,2) interleaved

__device__ __forceinline__ void load_edge(const int* __restrict__ ei, int E, int e,
                                          int& s, int& d) {
    if (g_flag) { s = ei[2 * e]; d = ei[2 * e + 1]; }
    else        { s = ei[e];     d = ei[e + E];     }
}

__global__ void k_prep(int n) {
    int i = blockIdx.x * blockDim.x + threadIdx.x;
    if (i == 0) g_cc = 0;
    if (i < n) g_deg[i] = 0;
}

// layout detection: contiguous reading of a true (2,E) edge list gives zero
// src==dst collisions (reference guarantees no self-loops)
__global__ void k_detect(const int* __restrict__ ei, int E) {
    int e = blockIdx.x * blockDim.x + threadIdx.x;
    if (e < E && ei[e] == ei[e + E]) atomicAdd(&g_cc, 1);
}

__global__ void k_setflag() { g_flag = (g_cc != 0) ? 1 : 0; }

__global__ void k_deg(const int* __restrict__ ei, int E) {
    int e = blockIdx.x * blockDim.x + threadIdx.x;
    if (e < E) {
        int s, d;
        load_edge(ei, E, e, s, d);
        atomicAdd(&g_deg[s], 1);
        atomicAdd(&g_deg[d], 1);
    }
}

__global__ void k_dis(int n) {
    int i = blockIdx.x * blockDim.x + threadIdx.x;
    if (i < n) g_dis[i] = 1.0f / sqrtf((float)g_deg[i] + 1.0f);
}

// graph ranges from sorted batch ids: g_gptr[g] = first node with batch >= g
__global__ void k_gptr(const int* __restrict__ batch, int n) {
    int i = blockIdx.x * blockDim.x + threadIdx.x;
    if (i > n) return;
    if (i == 0) {
        int b0 = batch[0];
        for (int g = 0; g <= b0; ++g) g_gptr[g] = 0;
    } else if (i == n) {
        int bl = batch[n - 1];
        for (int g = bl + 1; g <= NGRAPH; ++g) g_gptr[g] = n;
    } else {
        int bp = batch[i - 1], bc = batch[i];
        for (int g = bp + 1; g <= bc; ++g) g_gptr[g] = i;
    }
}

// ---- CSR construction: inclusive scan of deg -> g_row[1..n], g_row[0]=0 ----
__global__ void k_scan1(int n) {
    __shared__ int sh[SCAN_B];
    int i = blockIdx.x * SCAN_B + threadIdx.x;
    sh[threadIdx.x] = (i < n) ? g_deg[i] : 0;
    __syncthreads();
    for (int off = 1; off < SCAN_B; off <<= 1) {
        int t = (threadIdx.x >= off) ? sh[threadIdx.x - off] : 0;
        __syncthreads();
        sh[threadIdx.x] += t;
        __syncthreads();
    }
    if (i < n) g_row[i + 1] = sh[threadIdx.x];
    if (threadIdx.x == SCAN_B - 1) g_bsum[blockIdx.x] = sh[SCAN_B - 1];
}

__global__ void k_scan2(int nb) {
    if (threadIdx.x == 0 && blockIdx.x == 0) {
        int acc = 0;
        for (int b = 0; b < nb; ++b) { g_boff[b] = acc; acc += g_bsum[b]; }
    }
}

__global__ void k_scan3(int n) {
    int i = blockIdx.x * SCAN_B + threadIdx.x;
    if (i < n) g_row[i + 1] += g_boff[blockIdx.x];
    if (i == 0) g_row[0] = 0;
}

__global__ void k_cur(int n) {
    int i = blockIdx.x * blockDim.x + threadIdx.x;
    if (i < n) g_cur[i] = g_row[i];
}

__global__ void k_fill(const int* __restrict__ ei, int E) {
    int e = blockIdx.x * blockDim.x + threadIdx.x;
    if (e >= E) return;
    int s, d;
    load_edge(ei, E, e, s, d);
    int p = atomicAdd(&g_cur[d], 1); g_col[p] = s;
    int q = atomicAdd(&g_cur[s], 1); g_col[q] = d;
}

// ---- dense layers ----
// h = relu(x @ W_in + b_in); all fp32
__global__ void k_in(const float* __restrict__ x,
                     const float* __restrict__ W,
                     const float* __restrict__ b, int n) {
    int idx  = blockIdx.x * blockDim.x + threadIdx.x;
    int node = idx >> 6;
    int f    = idx & 63;
    if (node >= n) return;
    float acc = b[f];
    const float* xr = x + (long long)node * DIN;
    for (int k = 0; k < DIN; ++k)
        acc += xr[k] * W[k * HDIM + f];
    g_h[node * HDIM + f] = fmaxf(acc, 0.0f);
}

// t = h @ W  (reference order: HW first, then aggregate)
__global__ void k_hw(const float* __restrict__ W, int n) {
    int idx  = blockIdx.x * blockDim.x + threadIdx.x;
    int node = idx >> 6;
    int f    = idx & 63;
    if (node >= n) return;
    float acc = 0.0f;
    const float* hr = g_h + node * HDIM;
    for (int k = 0; k < HDIM; ++k)
        acc += hr[k] * W[k * HDIM + f];
    g_t[node * HDIM + f] = acc;
}

// CSR gather aggregation fused with self-loop + bias + relu:
// h_v = relu( dis_v * sum_u dis_u * t_u  +  dis_v^2 * t_v  +  b )
// one wave (64 lanes = 64 features) per node -> degree loop is wave-uniform
__global__ void k_gather(const float* __restrict__ b, int n) {
    int idx = blockIdx.x * blockDim.x + threadIdx.x;
    int v   = idx >> 6;
    int f   = idx & 63;
    if (v >= n) return;
    int beg = g_row[v], end = g_row[v + 1];
    float acc = 0.0f;
    for (int j = beg; j < end; ++j) {
        int u = g_col[j];
        acc += g_dis[u] * g_t[(size_t)u * HDIM + f];
    }
    float dv = g_dis[v];
    float r  = dv * acc + dv * dv * g_t[(size_t)v * HDIM + f] + b[f];
    g_h[(size_t)v * HDIM + f] = fmaxf(r, 0.0f);
}

// fused mean-pool + MLP head + log_softmax: one block (64 threads) per graph;
// batch sorted -> graph g owns contiguous node range, no atomics, cnt for free
__global__ void k_poolhead(const float* __restrict__ Wf1, const float* __restrict__ bf1,
                           const float* __restrict__ Wf2, const float* __restrict__ bf2,
                           float* __restrict__ out) {
    __shared__ float p[HDIM];
    __shared__ float z[DOUTD];
    int g = blockIdx.x;
    int f = threadIdx.x;
    int beg = g_gptr[g], end = g_gptr[g + 1];
    float s = 0.0f;
    for (int i = beg; i < end; ++i)
        s += g_h[(size_t)i * HDIM + f];
    float cnt = fmaxf((float)(end - beg), 1.0f);
    p[f] = s / cnt;
    __syncthreads();
    if (f < DOUTD) {
        float a = bf1[f];
        for (int k = 0; k < HDIM; ++k)
            a += p[k] * Wf1[k * DOUTD + f];
        z[f] = fmaxf(a, 0.0f);
    }
    __syncthreads();
    if (f == 0) {
        float l0 = bf2[0], l1 = bf2[1];
        for (int k = 0; k < DOUTD; ++k) {
            l0 += z[k] * Wf2[k * NCLS + 0];
            l1 += z[k] * Wf2[k * NCLS + 1];
        }
        float m   = fmaxf(l0, l1);
        float lse = m + logf(expf(l0 - m) + expf(l1 - m));
        out[g * NCLS + 0] = l0 - lse;
        out[g * NCLS + 1] = l1 - lse;
    }
}

extern "C" void kernel_launch(void* const* d_in, const int* in_sizes, int n_in,
                              void* d_out, int out_size, void* d_ws, size_t ws_size,
                              hipStream_t stream) {
    (void)d_ws; (void)ws_size; (void)out_size;

    const float* x   = (const float*)d_in[0];   // fp32 per reference setup
    const int*   ei  = (const int*)d_in[1];
    const int*   bat = (const int*)d_in[2];

    // by-size binding: skip scalar entries (num_graphs) after index 2
    const float* wp[10] = {nullptr};
    int wi = 0;
    for (int i = 3; i < n_in && wi < 10; ++i) {
        if (in_sizes[i] == 1) continue;
        wp[wi++] = (const float*)d_in[i];
    }
    const float* W_in = wp[0];
    const float* b_in = wp[1];
    const float* W1   = wp[2];
    const float* b1   = wp[3];
    const float* W2   = wp[4];
    const float* b2   = wp[5];
    const float* Wf1  = wp[6];
    const float* bf1  = wp[7];
    const float* Wf2  = wp[8];
    const float* bf2  = wp[9];

    const int n = in_sizes[0] / DIN;  // N nodes
    const int E = in_sizes[1] / 2;    // directed edges

    const int B = 256;
    int gE  = (E + B - 1) / B;
    int gN  = (n + B - 1) / B;
    int gN1 = (n + 1 + B - 1) / B;
    int gNH = (int)(((long long)n * HDIM + B - 1) / B);
    int nb  = (n + SCAN_B - 1) / SCAN_B;

    // degree + dis + graph ranges
    k_prep<<<gN, B, 0, stream>>>(n);
    k_detect<<<gE, B, 0, stream>>>(ei, E);
    k_setflag<<<1, 1, 0, stream>>>();
    k_deg<<<gE, B, 0, stream>>>(ei, E);
    k_dis<<<gN, B, 0, stream>>>(n);
    k_gptr<<<gN1, B, 0, stream>>>(bat, n);

    // CSR build
    k_scan1<<<nb, SCAN_B, 0, stream>>>(n);
    k_scan2<<<1, 1, 0, stream>>>(nb);
    k_scan3<<<nb, SCAN_B, 0, stream>>>(n);
    k_cur<<<gN, B, 0, stream>>>(n);
    k_fill<<<gE, B, 0, stream>>>(ei, E);

    // input layer
    k_in<<<gNH, B, 0, stream>>>(x, W_in, b_in, n);

    // conv 1
    k_hw<<<gNH, B, 0, stream>>>(W1, n);
    k_gather<<<gNH, B, 0, stream>>>(b1, n);

    // conv 2
    k_hw<<<gNH, B, 0, stream>>>(W2, n);
    k_gather<<<gNH, B, 0, stream>>>(b2, n);

    // fused pooling + head
    k_poolhead<<<NGRAPH, 64, 0, stream>>>(Wf1, bf1, Wf2, bf2, (float*)d_out);
}

// Round 10
// 1100.651 us; speedup vs baseline: 2.4543x; 1.5730x over previous
//
#include <hip/hip_runtime.h>
#include <hip/hip_bf16.h>

#define NMAX   100000
#define EMAX   1600000
#define NGRAPH 256
#define DIN    192
#define HDIM   64
#define DOUTD  32
#define NCLS   2
#define SCAN_B 512
#define TN     64          // node tile for dense kernels
#define XP     68          // LDS pitch: 272B rows -> float4-aligned, 2-way bank alias (free)

// All scratch in device globals — no dependence on d_ws / ws_size.
__device__ int   g_deg[NMAX];
__device__ float g_dis[NMAX];
__device__ float g_h[NMAX * HDIM];       // activations (gather output)
__device__ float g_t[NMAX * HDIM];       // h @ W (pre-aggregation)
__device__ int   g_row[NMAX + 1];        // CSR row pointers
__device__ int   g_cur[NMAX];            // fill cursors
__device__ int   g_col[2 * EMAX];        // CSR neighbor lists (both directions)
__device__ int   g_gptr[NGRAPH + 1];     // per-graph node ranges (batch is sorted)
__device__ int   g_bsum[256];
__device__ int   g_boff[256];
__device__ int   g_cc;
__device__ int   g_flag;                 // 0 = (2,E) contiguous, 1 = (E,2) interleaved

__device__ __forceinline__ void load_edge(const int* __restrict__ ei, int E, int e,
                                          int& s, int& d) {
    if (g_flag) { s = ei[2 * e]; d = ei[2 * e + 1]; }
    else        { s = ei[e];     d = ei[e + E];     }
}

__global__ void k_prep(int n) {
    int i = blockIdx.x * blockDim.x + threadIdx.x;
    if (i == 0) g_cc = 0;
    if (i < n) g_deg[i] = 0;
}

__global__ void k_detect(const int* __restrict__ ei, int E) {
    int e = blockIdx.x * blockDim.x + threadIdx.x;
    if (e < E && ei[e] == ei[e + E]) atomicAdd(&g_cc, 1);
}

__global__ void k_setflag() { g_flag = (g_cc != 0) ? 1 : 0; }

__global__ void k_deg(const int* __restrict__ ei, int E) {
    int e = blockIdx.x * blockDim.x + threadIdx.x;
    if (e < E) {
        int s, d;
        load_edge(ei, E, e, s, d);
        atomicAdd(&g_deg[s], 1);
        atomicAdd(&g_deg[d], 1);
    }
}

__global__ void k_dis(int n) {
    int i = blockIdx.x * blockDim.x + threadIdx.x;
    if (i < n) g_dis[i] = 1.0f / sqrtf((float)g_deg[i] + 1.0f);
}

__global__ void k_gptr(const int* __restrict__ batch, int n) {
    int i = blockIdx.x * blockDim.x + threadIdx.x;
    if (i > n) return;
    if (i == 0) {
        int b0 = batch[0];
        for (int g = 0; g <= b0; ++g) g_gptr[g] = 0;
    } else if (i == n) {
        int bl = batch[n - 1];
        for (int g = bl + 1; g <= NGRAPH; ++g) g_gptr[g] = n;
    } else {
        int bp = batch[i - 1], bc = batch[i];
        for (int g = bp + 1; g <= bc; ++g) g_gptr[g] = i;
    }
}

// ---- CSR construction ----
__global__ void k_scan1(int n) {
    __shared__ int sh[SCAN_B];
    int i = blockIdx.x * SCAN_B + threadIdx.x;
    sh[threadIdx.x] = (i < n) ? g_deg[i] : 0;
    __syncthreads();
    for (int off = 1; off < SCAN_B; off <<= 1) {
        int t = (threadIdx.x >= off) ? sh[threadIdx.x - off] : 0;
        __syncthreads();
        sh[threadIdx.x] += t;
        __syncthreads();
    }
    if (i < n) g_row[i + 1] = sh[threadIdx.x];
    if (threadIdx.x == SCAN_B - 1) g_bsum[blockIdx.x] = sh[SCAN_B - 1];
}

__global__ void k_scan2(int nb) {
    if (threadIdx.x == 0 && blockIdx.x == 0) {
        int acc = 0;
        for (int b = 0; b < nb; ++b) { g_boff[b] = acc; acc += g_bsum[b]; }
    }
}

__global__ void k_scan3(int n) {
    int i = blockIdx.x * SCAN_B + threadIdx.x;
    if (i < n) g_row[i + 1] += g_boff[blockIdx.x];
    if (i == 0) g_row[0] = 0;
}

__global__ void k_cur(int n) {
    int i = blockIdx.x * blockDim.x + threadIdx.x;
    if (i < n) g_cur[i] = g_row[i];
}

__global__ void k_fill(const int* __restrict__ ei, int E) {
    int e = blockIdx.x * blockDim.x + threadIdx.x;
    if (e >= E) return;
    int s, d;
    load_edge(ei, E, e, s, d);
    int p = atomicAdd(&g_cur[d], 1); g_col[p] = s;
    int q = atomicAdd(&g_cur[s], 1); g_col[q] = d;
}

// ---- fused input layer + conv1 HW: g_t = relu(x@W_in + b_in) @ W1 ----
// 64-node tile, 256 threads, 4x4 register micro-tile per thread.
__global__ __launch_bounds__(256) void k_inhw(const float* __restrict__ x,
                                              const float* __restrict__ Win,
                                              const float* __restrict__ bin,
                                              const float* __restrict__ W1, int n) {
    __shared__ float shx[TN][XP];
    __shared__ float shh[TN][XP];
    int tid = threadIdx.x;
    int fg  = tid & 15;          // feature group: cols 4*fg..4*fg+3
    int ng  = tid >> 4;          // node group:   rows 4*ng..4*ng+3
    int n0  = blockIdx.x * TN;

    float acc[4][4];
    #pragma unroll
    for (int i = 0; i < 4; ++i)
        #pragma unroll
        for (int j = 0; j < 4; ++j) acc[i][j] = 0.0f;

    for (int c = 0; c < DIN / 64; ++c) {
        int k0 = c * 64;
        __syncthreads();
        // stage x[n0..n0+63][k0..k0+63]
        #pragma unroll
        for (int p = 0; p < 4; ++p) {
            int row = p * 16 + (tid >> 4);
            int col = (tid & 15) * 4;
            float4 v = make_float4(0.f, 0.f, 0.f, 0.f);
            if (n0 + row < n)
                v = *(const float4*)(x + (size_t)(n0 + row) * DIN + k0 + col);
            *(float4*)&shx[row][col] = v;
        }
        __syncthreads();
        #pragma unroll 16
        for (int k = 0; k < 64; ++k) {
            float4 w = *(const float4*)(Win + (size_t)(k0 + k) * HDIM + fg * 4);
            #pragma unroll
            for (int i = 0; i < 4; ++i) {
                float xv = shx[ng * 4 + i][k];
                acc[i][0] += xv * w.x; acc[i][1] += xv * w.y;
                acc[i][2] += xv * w.z; acc[i][3] += xv * w.w;
            }
        }
    }
    // h tile = relu(acc + b) -> LDS
    float4 bb = *(const float4*)(bin + fg * 4);
    #pragma unroll
    for (int i = 0; i < 4; ++i) {
        float4 hv;
        hv.x = fmaxf(acc[i][0] + bb.x, 0.f);
        hv.y = fmaxf(acc[i][1] + bb.y, 0.f);
        hv.z = fmaxf(acc[i][2] + bb.z, 0.f);
        hv.w = fmaxf(acc[i][3] + bb.w, 0.f);
        *(float4*)&shh[ng * 4 + i][fg * 4] = hv;
    }
    __syncthreads();
    // t tile = h @ W1
    float a2[4][4];
    #pragma unroll
    for (int i = 0; i < 4; ++i)
        #pragma unroll
        for (int j = 0; j < 4; ++j) a2[i][j] = 0.0f;
    #pragma unroll 16
    for (int k = 0; k < 64; ++k) {
        float4 w = *(const float4*)(W1 + (size_t)k * HDIM + fg * 4);
        #pragma unroll
        for (int i = 0; i < 4; ++i) {
            float hv = shh[ng * 4 + i][k];
            a2[i][0] += hv * w.x; a2[i][1] += hv * w.y;
            a2[i][2] += hv * w.z; a2[i][3] += hv * w.w;
        }
    }
    #pragma unroll
    for (int i = 0; i < 4; ++i) {
        int node = n0 + ng * 4 + i;
        if (node < n)
            *(float4*)(g_t + (size_t)node * HDIM + fg * 4) =
                make_float4(a2[i][0], a2[i][1], a2[i][2], a2[i][3]);
    }
}

// ---- conv2 HW: g_t = g_h @ W2 (tiled, K=64) ----
__global__ __launch_bounds__(256) void k_hw2(const float* __restrict__ W2, int n) {
    __shared__ float shh[TN][XP];
    int tid = threadIdx.x;
    int fg  = tid & 15;
    int ng  = tid >> 4;
    int n0  = blockIdx.x * TN;

    #pragma unroll
    for (int p = 0; p < 4; ++p) {
        int row = p * 16 + (tid >> 4);
        int col = (tid & 15) * 4;
        float4 v = make_float4(0.f, 0.f, 0.f, 0.f);
        if (n0 + row < n)
            v = *(const float4*)(g_h + (size_t)(n0 + row) * HDIM + col);
        *(float4*)&shh[row][col] = v;
    }
    __syncthreads();
    float acc[4][4];
    #pragma unroll
    for (int i = 0; i < 4; ++i)
        #pragma unroll
        for (int j = 0; j < 4; ++j) acc[i][j] = 0.0f;
    #pragma unroll 16
    for (int k = 0; k < 64; ++k) {
        float4 w = *(const float4*)(W2 + (size_t)k * HDIM + fg * 4);
        #pragma unroll
        for (int i = 0; i < 4; ++i) {
            float hv = shh[ng * 4 + i][k];
            acc[i][0] += hv * w.x; acc[i][1] += hv * w.y;
            acc[i][2] += hv * w.z; acc[i][3] += hv * w.w;
        }
    }
    #pragma unroll
    for (int i = 0; i < 4; ++i) {
        int node = n0 + ng * 4 + i;
        if (node < n)
            *(float4*)(g_t + (size_t)node * HDIM + fg * 4) =
                make_float4(acc[i][0], acc[i][1], acc[i][2], acc[i][3]);
    }
}

// CSR gather + self-loop + bias + relu; one wave per node; 4x unrolled
__global__ void k_gather(const float* __restrict__ b, int n) {
    int idx = blockIdx.x * blockDim.x + threadIdx.x;
    int v   = idx >> 6;
    int f   = idx & 63;
    if (v >= n) return;
    int beg = g_row[v], end = g_row[v + 1];
    float acc = 0.0f;
    int j = beg;
    for (; j + 4 <= end; j += 4) {
        int u0 = g_col[j], u1 = g_col[j + 1], u2 = g_col[j + 2], u3 = g_col[j + 3];
        float s0 = g_dis[u0] * g_t[(size_t)u0 * HDIM + f];
        float s1 = g_dis[u1] * g_t[(size_t)u1 * HDIM + f];
        float s2 = g_dis[u2] * g_t[(size_t)u2 * HDIM + f];
        float s3 = g_dis[u3] * g_t[(size_t)u3 * HDIM + f];
        acc += (s0 + s1) + (s2 + s3);
    }
    for (; j < end; ++j) {
        int u = g_col[j];
        acc += g_dis[u] * g_t[(size_t)u * HDIM + f];
    }
    float dv = g_dis[v];
    float r  = dv * acc + dv * dv * g_t[(size_t)v * HDIM + f] + b[f];
    g_h[(size_t)v * HDIM + f] = fmaxf(r, 0.0f);
}

// fused mean-pool + MLP head + log_softmax; 4 waves per graph
__global__ void k_poolhead(const float* __restrict__ Wf1, const float* __restrict__ bf1,
                           const float* __restrict__ Wf2, const float* __restrict__ bf2,
                           float* __restrict__ out) {
    __shared__ float ps[4][HDIM];
    __shared__ float p[HDIM];
    __shared__ float z[DOUTD];
    int g   = blockIdx.x;
    int tid = threadIdx.x;
    int f   = tid & 63, q = tid >> 6;
    int beg = g_gptr[g], end = g_gptr[g + 1];
    float s = 0.0f;
    for (int i = beg + q; i < end; i += 4)
        s += g_h[(size_t)i * HDIM + f];
    ps[q][f] = s;
    __syncthreads();
    if (tid < HDIM) {
        float cnt = fmaxf((float)(end - beg), 1.0f);
        p[tid] = (ps[0][tid] + ps[1][tid] + ps[2][tid] + ps[3][tid]) / cnt;
    }
    __syncthreads();
    if (tid < DOUTD) {
        float a = bf1[tid];
        for (int k = 0; k < HDIM; ++k)
            a += p[k] * Wf1[k * DOUTD + tid];
        z[tid] = fmaxf(a, 0.0f);
    }
    __syncthreads();
    if (tid == 0) {
        float l0 = bf2[0], l1 = bf2[1];
        for (int k = 0; k < DOUTD; ++k) {
            l0 += z[k] * Wf2[k * NCLS + 0];
            l1 += z[k] * Wf2[k * NCLS + 1];
        }
        float m   = fmaxf(l0, l1);
        float lse = m + logf(expf(l0 - m) + expf(l1 - m));
        out[g * NCLS + 0] = l0 - lse;
        out[g * NCLS + 1] = l1 - lse;
    }
}

extern "C" void kernel_launch(void* const* d_in, const int* in_sizes, int n_in,
                              void* d_out, int out_size, void* d_ws, size_t ws_size,
                              hipStream_t stream) {
    (void)d_ws; (void)ws_size; (void)out_size;

    const float* x   = (const float*)d_in[0];
    const int*   ei  = (const int*)d_in[1];
    const int*   bat = (const int*)d_in[2];

    const float* wp[10] = {nullptr};
    int wi = 0;
    for (int i = 3; i < n_in && wi < 10; ++i) {
        if (in_sizes[i] == 1) continue;
        wp[wi++] = (const float*)d_in[i];
    }
    const float* W_in = wp[0];
    const float* b_in = wp[1];
    const float* W1   = wp[2];
    const float* b1   = wp[3];
    const float* W2   = wp[4];
    const float* b2   = wp[5];
    const float* Wf1  = wp[6];
    const float* bf1  = wp[7];
    const float* Wf2  = wp[8];
    const float* bf2  = wp[9];

    const int n = in_sizes[0] / DIN;
    const int E = in_sizes[1] / 2;

    const int B = 256;
    int gE   = (E + B - 1) / B;
    int gN   = (n + B - 1) / B;
    int gN1  = (n + 1 + B - 1) / B;
    int gNH  = (int)(((long long)n * HDIM + B - 1) / B);
    int nb   = (n + SCAN_B - 1) / SCAN_B;
    int gTile = (n + TN - 1) / TN;

    k_prep<<<gN, B, 0, stream>>>(n);
    k_detect<<<gE, B, 0, stream>>>(ei, E);
    k_setflag<<<1, 1, 0, stream>>>();
    k_deg<<<gE, B, 0, stream>>>(ei, E);
    k_dis<<<gN, B, 0, stream>>>(n);
    k_gptr<<<gN1, B, 0, stream>>>(bat, n);

    k_scan1<<<nb, SCAN_B, 0, stream>>>(n);
    k_scan2<<<1, 1, 0, stream>>>(nb);
    k_scan3<<<nb, SCAN_B, 0, stream>>>(n);
    k_cur<<<gN, B, 0, stream>>>(n);
    k_fill<<<gE, B, 0, stream>>>(ei, E);

    // fused input layer + conv1 HW
    k_inhw<<<gTile, 256, 0, stream>>>(x, W_in, b_in, W1, n);
    k_gather<<<gNH, B, 0, stream>>>(b1, n);

    // conv 2
    k_hw2<<<gTile, 256, 0, stream>>>(W2, n);
    k_gather<<<gNH, B, 0, stream>>>(b2, n);

    k_poolhead<<<NGRAPH, 256, 0, stream>>>(Wf1, bf1, Wf2, bf2, (float*)d_out);
}

// Round 11
// 848.200 us; speedup vs baseline: 3.1848x; 1.2976x over previous
//
#include <hip/hip_runtime.h>
#include <hip/hip_bf16.h>

#define NMAX   100000
#define EMAX   1600000
#define NGRAPH 256
#define DIN    192
#define HDIM   64
#define DOUTD  32
#define NCLS   2
#define SCAN_B 512
#define TN     64          // node tile for dense kernels
#define XP     68          // LDS pitch for dense tiles
#define NB_SHIFT 8                          // 256 nodes per bucket
#define NBUCK  ((NMAX >> NB_SHIFT) + 1)     // 391
#define T1E    2048                         // edges per stage super-tile
#define P2CAP  15872                        // phase-2 LDS col capacity (62 KB)

// All scratch in device globals — no dependence on d_ws / ws_size.
__device__ int   g_deg[NMAX];
__device__ float g_dis[NMAX];
__device__ float g_h[NMAX * HDIM];       // activations (gather output)
__device__ float g_t[NMAX * HDIM];       // h @ W (pre-aggregation)
__device__ int   g_row[NMAX + 1];        // CSR row pointers
__device__ int   g_col[2 * EMAX];        // CSR neighbor lists
__device__ int2  g_stage[2 * EMAX];      // bucketed (dest,src) staging
__device__ int   g_bcur[NBUCK];          // bucket fill cursors
__device__ int   g_gptr[NGRAPH + 1];     // per-graph node ranges (batch sorted)
__device__ int   g_bsum[256];
__device__ int   g_boff[256];
__device__ int   g_cc;
__device__ int   g_flag;                 // 0 = (2,E) contiguous, 1 = (E,2) interleaved

__device__ __forceinline__ void load_edge(const int* __restrict__ ei, int E, int e,
                                          int& s, int& d) {
    if (g_flag) { s = ei[2 * e]; d = ei[2 * e + 1]; }
    else        { s = ei[e];     d = ei[e + E];     }
}

__global__ void k_prep(int n) {
    int i = blockIdx.x * blockDim.x + threadIdx.x;
    if (i == 0) g_cc = 0;
    if (i < n) g_deg[i] = 0;
}

__global__ void k_detect(const int* __restrict__ ei, int E) {
    int e = blockIdx.x * blockDim.x + threadIdx.x;
    if (e < E && ei[e] == ei[e + E]) atomicAdd(&g_cc, 1);
}

__global__ void k_setflag() { g_flag = (g_cc != 0) ? 1 : 0; }

// degree = histogram of ALL 2E endpoint ids — layout-independent
__global__ void k_deghist(const int* __restrict__ ei, int E2) {
    int i = blockIdx.x * blockDim.x + threadIdx.x;
    if (i < E2) atomicAdd(&g_deg[ei[i]], 1);
}

__global__ void k_dis(int n) {
    int i = blockIdx.x * blockDim.x + threadIdx.x;
    if (i < n) g_dis[i] = 1.0f / sqrtf((float)g_deg[i] + 1.0f);
}

__global__ void k_gptr(const int* __restrict__ batch, int n) {
    int i = blockIdx.x * blockDim.x + threadIdx.x;
    if (i > n) return;
    if (i == 0) {
        int b0 = batch[0];
        for (int g = 0; g <= b0; ++g) g_gptr[g] = 0;
    } else if (i == n) {
        int bl = batch[n - 1];
        for (int g = bl + 1; g <= NGRAPH; ++g) g_gptr[g] = n;
    } else {
        int bp = batch[i - 1], bc = batch[i];
        for (int g = bp + 1; g <= bc; ++g) g_gptr[g] = i;
    }
}

// ---- row-pointer scan ----
__global__ void k_scan1(int n) {
    __shared__ int sh[SCAN_B];
    int i = blockIdx.x * SCAN_B + threadIdx.x;
    sh[threadIdx.x] = (i < n) ? g_deg[i] : 0;
    __syncthreads();
    for (int off = 1; off < SCAN_B; off <<= 1) {
        int t = (threadIdx.x >= off) ? sh[threadIdx.x - off] : 0;
        __syncthreads();
        sh[threadIdx.x] += t;
        __syncthreads();
    }
    if (i < n) g_row[i + 1] = sh[threadIdx.x];
    if (threadIdx.x == SCAN_B - 1) g_bsum[blockIdx.x] = sh[SCAN_B - 1];
}

__global__ void k_scan2(int nb) {
    if (threadIdx.x == 0 && blockIdx.x == 0) {
        int acc = 0;
        for (int b = 0; b < nb; ++b) { g_boff[b] = acc; acc += g_bsum[b]; }
    }
}

__global__ void k_scan3(int n) {
    int i = blockIdx.x * SCAN_B + threadIdx.x;
    if (i < n) g_row[i + 1] += g_boff[blockIdx.x];
    if (i == 0) g_row[0] = 0;
}

// bucket cursors start at the bucket's row-prefix (stage region == col region)
__global__ void k_binit(int n) {
    int b = blockIdx.x * blockDim.x + threadIdx.x;
    if (b < NBUCK) {
        int v0 = b << NB_SHIFT;
        g_bcur[b] = g_row[v0 < n ? v0 : n];
    }
}

// ---- phase 1: stage endpoint pairs grouped by 256-node bucket ----
__global__ __launch_bounds__(256) void k_stage(const int* __restrict__ ei, int E) {
    __shared__ int2 sbuf[2 * T1E];           // 4096 pairs, 32 KB
    __shared__ int  scnt[NBUCK], soff[NBUCK], sput[NBUCK], sbase[NBUCK];
    __shared__ int  sc[512];
    int tid = threadIdx.x;
    int e0  = blockIdx.x * T1E;
    for (int b = tid; b < NBUCK; b += 256) { scnt[b] = 0; sput[b] = 0; }
    __syncthreads();

    int s[8], d[8];
    #pragma unroll
    for (int it = 0; it < 8; ++it) {
        int e = e0 + it * 256 + tid;
        if (e < E) {
            load_edge(ei, E, e, s[it], d[it]);
            atomicAdd(&scnt[d[it] >> NB_SHIFT], 1);
            atomicAdd(&scnt[s[it] >> NB_SHIFT], 1);
        } else s[it] = -1;
    }
    __syncthreads();

    // inclusive Hillis-Steele scan over 512-padded counts
    sc[tid]       = (tid < NBUCK) ? scnt[tid] : 0;
    sc[tid + 256] = (tid + 256 < NBUCK) ? scnt[tid + 256] : 0;
    __syncthreads();
    for (int off = 1; off < 512; off <<= 1) {
        int a = (tid >= off) ? sc[tid - off] : 0;
        int b = (tid + 256 >= off) ? sc[tid + 256 - off] : 0;
        __syncthreads();
        sc[tid] += a; sc[tid + 256] += b;
        __syncthreads();
    }
    for (int b = tid; b < NBUCK; b += 256) {
        soff[b] = sc[b] - scnt[b];                       // exclusive
        if (scnt[b] > 0) sbase[b] = atomicAdd(&g_bcur[b], scnt[b]);
    }
    __syncthreads();

    #pragma unroll
    for (int it = 0; it < 8; ++it) {
        if (s[it] >= 0) {
            int bd = d[it] >> NB_SHIFT;
            sbuf[soff[bd] + atomicAdd(&sput[bd], 1)] = make_int2(d[it], s[it]);
            int bs = s[it] >> NB_SHIFT;
            sbuf[soff[bs] + atomicAdd(&sput[bs], 1)] = make_int2(s[it], d[it]);
        }
    }
    __syncthreads();

    int total = sc[NBUCK - 1];
    for (int i = tid; i < total; i += 256) {
        int2 pr = sbuf[i];
        int  b  = pr.x >> NB_SHIFT;
        g_stage[sbase[b] + (i - soff[b])] = pr;
    }
}

// ---- phase 2: per-bucket LDS scatter, coalesced col writeout ----
__global__ __launch_bounds__(256) void k_scatter(int n) {
    __shared__ int cols[P2CAP];
    __shared__ int cur[256];
    int b  = blockIdx.x;
    int v0 = b << NB_SHIFT;
    if (v0 >= n) return;
    int v1   = min(v0 + 256, n);
    int base = g_row[v0];
    int len  = g_row[v1] - base;
    int tid  = threadIdx.x;
    if (v0 + tid < v1) cur[tid] = g_row[v0 + tid] - base;
    __syncthreads();
    for (int i = tid; i < len; i += 256) {
        int2 pr  = g_stage[base + i];
        int  pos = atomicAdd(&cur[pr.x - v0], 1);
        if (pos < P2CAP) cols[pos] = pr.y;
        else             g_col[base + pos] = pr.y;   // never expected; correct anyway
    }
    __syncthreads();
    int lim = len < P2CAP ? len : P2CAP;
    for (int i = tid; i < lim; i += 256) g_col[base + i] = cols[i];
}

// ---- fused input layer + conv1 HW: g_t = relu(x@W_in + b_in) @ W1 ----
__global__ __launch_bounds__(256) void k_inhw(const float* __restrict__ x,
                                              const float* __restrict__ Win,
                                              const float* __restrict__ bin,
                                              const float* __restrict__ W1, int n) {
    __shared__ float shx[TN][XP];
    __shared__ float shh[TN][XP];
    int tid = threadIdx.x;
    int fg  = tid & 15;
    int ng  = tid >> 4;
    int n0  = blockIdx.x * TN;

    float acc[4][4];
    #pragma unroll
    for (int i = 0; i < 4; ++i)
        #pragma unroll
        for (int j = 0; j < 4; ++j) acc[i][j] = 0.0f;

    for (int c = 0; c < DIN / 64; ++c) {
        int k0 = c * 64;
        __syncthreads();
        #pragma unroll
        for (int p = 0; p < 4; ++p) {
            int row = p * 16 + (tid >> 4);
            int col = (tid & 15) * 4;
            float4 v = make_float4(0.f, 0.f, 0.f, 0.f);
            if (n0 + row < n)
                v = *(const float4*)(x + (size_t)(n0 + row) * DIN + k0 + col);
            *(float4*)&shx[row][col] = v;
        }
        __syncthreads();
        #pragma unroll 16
        for (int k = 0; k < 64; ++k) {
            float4 w = *(const float4*)(Win + (size_t)(k0 + k) * HDIM + fg * 4);
            #pragma unroll
            for (int i = 0; i < 4; ++i) {
                float xv = shx[ng * 4 + i][k];
                acc[i][0] += xv * w.x; acc[i][1] += xv * w.y;
                acc[i][2] += xv * w.z; acc[i][3] += xv * w.w;
            }
        }
    }
    float4 bb = *(const float4*)(bin + fg * 4);
    #pragma unroll
    for (int i = 0; i < 4; ++i) {
        float4 hv;
        hv.x = fmaxf(acc[i][0] + bb.x, 0.f);
        hv.y = fmaxf(acc[i][1] + bb.y, 0.f);
        hv.z = fmaxf(acc[i][2] + bb.z, 0.f);
        hv.w = fmaxf(acc[i][3] + bb.w, 0.f);
        *(float4*)&shh[ng * 4 + i][fg * 4] = hv;
    }
    __syncthreads();
    float a2[4][4];
    #pragma unroll
    for (int i = 0; i < 4; ++i)
        #pragma unroll
        for (int j = 0; j < 4; ++j) a2[i][j] = 0.0f;
    #pragma unroll 16
    for (int k = 0; k < 64; ++k) {
        float4 w = *(const float4*)(W1 + (size_t)k * HDIM + fg * 4);
        #pragma unroll
        for (int i = 0; i < 4; ++i) {
            float hv = shh[ng * 4 + i][k];
            a2[i][0] += hv * w.x; a2[i][1] += hv * w.y;
            a2[i][2] += hv * w.z; a2[i][3] += hv * w.w;
        }
    }
    #pragma unroll
    for (int i = 0; i < 4; ++i) {
        int node = n0 + ng * 4 + i;
        if (node < n)
            *(float4*)(g_t + (size_t)node * HDIM + fg * 4) =
                make_float4(a2[i][0], a2[i][1], a2[i][2], a2[i][3]);
    }
}

// ---- conv2 HW: g_t = g_h @ W2 ----
__global__ __launch_bounds__(256) void k_hw2(const float* __restrict__ W2, int n) {
    __shared__ float shh[TN][XP];
    int tid = threadIdx.x;
    int fg  = tid & 15;
    int ng  = tid >> 4;
    int n0  = blockIdx.x * TN;

    #pragma unroll
    for (int p = 0; p < 4; ++p) {
        int row = p * 16 + (tid >> 4);
        int col = (tid & 15) * 4;
        float4 v = make_float4(0.f, 0.f, 0.f, 0.f);
        if (n0 + row < n)
            v = *(const float4*)(g_h + (size_t)(n0 + row) * HDIM + col);
        *(float4*)&shh[row][col] = v;
    }
    __syncthreads();
    float acc[4][4];
    #pragma unroll
    for (int i = 0; i < 4; ++i)
        #pragma unroll
        for (int j = 0; j < 4; ++j) acc[i][j] = 0.0f;
    #pragma unroll 16
    for (int k = 0; k < 64; ++k) {
        float4 w = *(const float4*)(W2 + (size_t)k * HDIM + fg * 4);
        #pragma unroll
        for (int i = 0; i < 4; ++i) {
            float hv = shh[ng * 4 + i][k];
            acc[i][0] += hv * w.x; acc[i][1] += hv * w.y;
            acc[i][2] += hv * w.z; acc[i][3] += hv * w.w;
        }
    }
    #pragma unroll
    for (int i = 0; i < 4; ++i) {
        int node = n0 + ng * 4 + i;
        if (node < n)
            *(float4*)(g_t + (size_t)node * HDIM + fg * 4) =
                make_float4(acc[i][0], acc[i][1], acc[i][2], acc[i][3]);
    }
}

// CSR gather + self-loop + bias + relu; one wave per node; 8x unrolled
__global__ void k_gather(const float* __restrict__ b, int n) {
    int idx = blockIdx.x * blockDim.x + threadIdx.x;
    int v   = idx >> 6;
    int f   = idx & 63;
    if (v >= n) return;
    int beg = g_row[v], end = g_row[v + 1];
    float acc = 0.0f;
    int j = beg;
    for (; j + 8 <= end; j += 8) {
        int u0 = g_col[j],     u1 = g_col[j + 1], u2 = g_col[j + 2], u3 = g_col[j + 3];
        int u4 = g_col[j + 4], u5 = g_col[j + 5], u6 = g_col[j + 6], u7 = g_col[j + 7];
        float s0 = g_dis[u0] * g_t[(size_t)u0 * HDIM + f];
        float s1 = g_dis[u1] * g_t[(size_t)u1 * HDIM + f];
        float s2 = g_dis[u2] * g_t[(size_t)u2 * HDIM + f];
        float s3 = g_dis[u3] * g_t[(size_t)u3 * HDIM + f];
        float s4 = g_dis[u4] * g_t[(size_t)u4 * HDIM + f];
        float s5 = g_dis[u5] * g_t[(size_t)u5 * HDIM + f];
        float s6 = g_dis[u6] * g_t[(size_t)u6 * HDIM + f];
        float s7 = g_dis[u7] * g_t[(size_t)u7 * HDIM + f];
        acc += ((s0 + s1) + (s2 + s3)) + ((s4 + s5) + (s6 + s7));
    }
    for (; j < end; ++j) {
        int u = g_col[j];
        acc += g_dis[u] * g_t[(size_t)u * HDIM + f];
    }
    float dv = g_dis[v];
    float r  = dv * acc + dv * dv * g_t[(size_t)v * HDIM + f] + b[f];
    g_h[(size_t)v * HDIM + f] = fmaxf(r, 0.0f);
}

// fused mean-pool + MLP head + log_softmax; 4 waves per graph
__global__ void k_poolhead(const float* __restrict__ Wf1, const float* __restrict__ bf1,
                           const float* __restrict__ Wf2, const float* __restrict__ bf2,
                           float* __restrict__ out) {
    __shared__ float ps[4][HDIM];
    __shared__ float p[HDIM];
    __shared__ float z[DOUTD];
    int g   = blockIdx.x;
    int tid = threadIdx.x;
    int f   = tid & 63, q = tid >> 6;
    int beg = g_gptr[g], end = g_gptr[g + 1];
    float s = 0.0f;
    for (int i = beg + q; i < end; i += 4)
        s += g_h[(size_t)i * HDIM + f];
    ps[q][f] = s;
    __syncthreads();
    if (tid < HDIM) {
        float cnt = fmaxf((float)(end - beg), 1.0f);
        p[tid] = (ps[0][tid] + ps[1][tid] + ps[2][tid] + ps[3][tid]) / cnt;
    }
    __syncthreads();
    if (tid < DOUTD) {
        float a = bf1[tid];
        for (int k = 0; k < HDIM; ++k)
            a += p[k] * Wf1[k * DOUTD + tid];
        z[tid] = fmaxf(a, 0.0f);
    }
    __syncthreads();
    if (tid == 0) {
        float l0 = bf2[0], l1 = bf2[1];
        for (int k = 0; k < DOUTD; ++k) {
            l0 += z[k] * Wf2[k * NCLS + 0];
            l1 += z[k] * Wf2[k * NCLS + 1];
        }
        float m   = fmaxf(l0, l1);
        float lse = m + logf(expf(l0 - m) + expf(l1 - m));
        out[g * NCLS + 0] = l0 - lse;
        out[g * NCLS + 1] = l1 - lse;
    }
}

extern "C" void kernel_launch(void* const* d_in, const int* in_sizes, int n_in,
                              void* d_out, int out_size, void* d_ws, size_t ws_size,
                              hipStream_t stream) {
    (void)d_ws; (void)ws_size; (void)out_size;

    const float* x   = (const float*)d_in[0];
    const int*   ei  = (const int*)d_in[1];
    const int*   bat = (const int*)d_in[2];

    const float* wp[10] = {nullptr};
    int wi = 0;
    for (int i = 3; i < n_in && wi < 10; ++i) {
        if (in_sizes[i] == 1) continue;
        wp[wi++] = (const float*)d_in[i];
    }
    const float* W_in = wp[0];
    const float* b_in = wp[1];
    const float* W1   = wp[2];
    const float* b1   = wp[3];
    const float* W2   = wp[4];
    const float* b2   = wp[5];
    const float* Wf1  = wp[6];
    const float* bf1  = wp[7];
    const float* Wf2  = wp[8];
    const float* bf2  = wp[9];

    const int n = in_sizes[0] / DIN;
    const int E = in_sizes[1] / 2;

    const int B = 256;
    int gE    = (E + B - 1) / B;
    int gE2   = (2 * E + B - 1) / B;
    int gN    = (n + B - 1) / B;
    int gN1   = (n + 1 + B - 1) / B;
    int gNH   = (int)(((long long)n * HDIM + B - 1) / B);
    int nb    = (n + SCAN_B - 1) / SCAN_B;
    int gTile = (n + TN - 1) / TN;
    int gStage = (E + T1E - 1) / T1E;
    int gBk   = (NBUCK + B - 1) / B;

    k_prep<<<gN, B, 0, stream>>>(n);
    k_detect<<<gE, B, 0, stream>>>(ei, E);
    k_setflag<<<1, 1, 0, stream>>>();
    k_deghist<<<gE2, B, 0, stream>>>(ei, 2 * E);
    k_dis<<<gN, B, 0, stream>>>(n);
    k_gptr<<<gN1, B, 0, stream>>>(bat, n);

    k_scan1<<<nb, SCAN_B, 0, stream>>>(n);
    k_scan2<<<1, 1, 0, stream>>>(nb);
    k_scan3<<<nb, SCAN_B, 0, stream>>>(n);
    k_binit<<<gBk, B, 0, stream>>>(n);
    k_stage<<<gStage, 256, 0, stream>>>(ei, E);
    k_scatter<<<NBUCK, 256, 0, stream>>>(n);

    // fused input layer + conv1 HW
    k_inhw<<<gTile, 256, 0, stream>>>(x, W_in, b_in, W1, n);
    k_gather<<<gNH, B, 0, stream>>>(b1, n);

    // conv 2
    k_hw2<<<gTile, 256, 0, stream>>>(W2, n);
    k_gather<<<gNH, B, 0, stream>>>(b2, n);

    k_poolhead<<<NGRAPH, 256, 0, stream>>>(Wf1, bf1, Wf2, bf2, (float*)d_out);
}

// Round 12
// 680.485 us; speedup vs baseline: 3.9697x; 1.2465x over previous
//
#include <hip/hip_runtime.h>
#include <hip/hip_bf16.h>
#include <hip/hip_fp16.h>

#define NMAX   100000
#define EMAX   1600000
#define NGRAPH 256
#define DIN    192
#define HDIM   64
#define DOUTD  32
#define NCLS   2
#define SCAN_B 512
#define TN     64          // node tile for dense kernels
#define XP     68          // LDS pitch for dense tiles
#define NB_SHIFT 8                          // 256 nodes per bucket
#define NBUCK  ((NMAX >> NB_SHIFT) + 1)     // 391
#define T1E    2048                         // edges per stage super-tile
#define P2CAP  15872                        // phase-2 LDS col capacity (62 KB)

// All scratch in device globals — no dependence on d_ws / ws_size.
__device__ int    g_deg[NMAX];
__device__ float  g_dis[NMAX];
__device__ float  g_h[NMAX * HDIM];       // activations (gather output)
__device__ __half g_t16[NMAX * HDIM];     // fp16 messages: dis_u * (h @ W)_u
__device__ int    g_row[NMAX + 1];        // CSR row pointers
__device__ int    g_col[2 * EMAX];        // CSR neighbor lists
__device__ int2   g_stage[2 * EMAX];      // bucketed (dest,src) staging
__device__ int    g_bcur[NBUCK];          // bucket fill cursors
__device__ int    g_gptr[NGRAPH + 1];     // per-graph node ranges (batch sorted)
__device__ int    g_bsum[256];
__device__ int    g_boff[256];
__device__ int    g_cc;
__device__ int    g_flag;                 // 0 = (2,E) contiguous, 1 = (E,2) interleaved

__device__ __forceinline__ void load_edge(const int* __restrict__ ei, int E, int e,
                                          int& s, int& d) {
    if (g_flag) { s = ei[2 * e]; d = ei[2 * e + 1]; }
    else        { s = ei[e];     d = ei[e + E];     }
}

__global__ void k_prep(int n) {
    int i = blockIdx.x * blockDim.x + threadIdx.x;
    if (i == 0) g_cc = 0;
    if (i < n) g_deg[i] = 0;
}

__global__ void k_detect(const int* __restrict__ ei, int E) {
    int e = blockIdx.x * blockDim.x + threadIdx.x;
    if (e < E && ei[e] == ei[e + E]) atomicAdd(&g_cc, 1);
}

__global__ void k_setflag() { g_flag = (g_cc != 0) ? 1 : 0; }

// degree = histogram of ALL 2E endpoint ids — layout-independent
__global__ void k_deghist(const int* __restrict__ ei, int E2) {
    int i = blockIdx.x * blockDim.x + threadIdx.x;
    if (i < E2) atomicAdd(&g_deg[ei[i]], 1);
}

__global__ void k_dis(int n) {
    int i = blockIdx.x * blockDim.x + threadIdx.x;
    if (i < n) g_dis[i] = 1.0f / sqrtf((float)g_deg[i] + 1.0f);
}

__global__ void k_gptr(const int* __restrict__ batch, int n) {
    int i = blockIdx.x * blockDim.x + threadIdx.x;
    if (i > n) return;
    if (i == 0) {
        int b0 = batch[0];
        for (int g = 0; g <= b0; ++g) g_gptr[g] = 0;
    } else if (i == n) {
        int bl = batch[n - 1];
        for (int g = bl + 1; g <= NGRAPH; ++g) g_gptr[g] = n;
    } else {
        int bp = batch[i - 1], bc = batch[i];
        for (int g = bp + 1; g <= bc; ++g) g_gptr[g] = i;
    }
}

// ---- row-pointer scan ----
__global__ void k_scan1(int n) {
    __shared__ int sh[SCAN_B];
    int i = blockIdx.x * SCAN_B + threadIdx.x;
    sh[threadIdx.x] = (i < n) ? g_deg[i] : 0;
    __syncthreads();
    for (int off = 1; off < SCAN_B; off <<= 1) {
        int t = (threadIdx.x >= off) ? sh[threadIdx.x - off] : 0;
        __syncthreads();
        sh[threadIdx.x] += t;
        __syncthreads();
    }
    if (i < n) g_row[i + 1] = sh[threadIdx.x];
    if (threadIdx.x == SCAN_B - 1) g_bsum[blockIdx.x] = sh[SCAN_B - 1];
}

__global__ void k_scan2(int nb) {
    if (threadIdx.x == 0 && blockIdx.x == 0) {
        int acc = 0;
        for (int b = 0; b < nb; ++b) { g_boff[b] = acc; acc += g_bsum[b]; }
    }
}

__global__ void k_scan3(int n) {
    int i = blockIdx.x * SCAN_B + threadIdx.x;
    if (i < n) g_row[i + 1] += g_boff[blockIdx.x];
    if (i == 0) g_row[0] = 0;
}

__global__ void k_binit(int n) {
    int b = blockIdx.x * blockDim.x + threadIdx.x;
    if (b < NBUCK) {
        int v0 = b << NB_SHIFT;
        g_bcur[b] = g_row[v0 < n ? v0 : n];
    }
}

// ---- phase 1: stage endpoint pairs grouped by 256-node bucket ----
__global__ __launch_bounds__(256) void k_stage(const int* __restrict__ ei, int E) {
    __shared__ int2 sbuf[2 * T1E];           // 4096 pairs, 32 KB
    __shared__ int  scnt[NBUCK], soff[NBUCK], sput[NBUCK], sbase[NBUCK];
    __shared__ int  sc[512];
    int tid = threadIdx.x;
    int e0  = blockIdx.x * T1E;
    for (int b = tid; b < NBUCK; b += 256) { scnt[b] = 0; sput[b] = 0; }
    __syncthreads();

    int s[8], d[8];
    #pragma unroll
    for (int it = 0; it < 8; ++it) {
        int e = e0 + it * 256 + tid;
        if (e < E) {
            load_edge(ei, E, e, s[it], d[it]);
            atomicAdd(&scnt[d[it] >> NB_SHIFT], 1);
            atomicAdd(&scnt[s[it] >> NB_SHIFT], 1);
        } else s[it] = -1;
    }
    __syncthreads();

    sc[tid]       = (tid < NBUCK) ? scnt[tid] : 0;
    sc[tid + 256] = (tid + 256 < NBUCK) ? scnt[tid + 256] : 0;
    __syncthreads();
    for (int off = 1; off < 512; off <<= 1) {
        int a = (tid >= off) ? sc[tid - off] : 0;
        int b = (tid + 256 >= off) ? sc[tid + 256 - off] : 0;
        __syncthreads();
        sc[tid] += a; sc[tid + 256] += b;
        __syncthreads();
    }
    for (int b = tid; b < NBUCK; b += 256) {
        soff[b] = sc[b] - scnt[b];
        if (scnt[b] > 0) sbase[b] = atomicAdd(&g_bcur[b], scnt[b]);
    }
    __syncthreads();

    #pragma unroll
    for (int it = 0; it < 8; ++it) {
        if (s[it] >= 0) {
            int bd = d[it] >> NB_SHIFT;
            sbuf[soff[bd] + atomicAdd(&sput[bd], 1)] = make_int2(d[it], s[it]);
            int bs = s[it] >> NB_SHIFT;
            sbuf[soff[bs] + atomicAdd(&sput[bs], 1)] = make_int2(s[it], d[it]);
        }
    }
    __syncthreads();

    int total = sc[NBUCK - 1];
    for (int i = tid; i < total; i += 256) {
        int2 pr = sbuf[i];
        int  b  = pr.x >> NB_SHIFT;
        g_stage[sbase[b] + (i - soff[b])] = pr;
    }
}

// ---- phase 2: per-bucket LDS scatter, coalesced col writeout ----
__global__ __launch_bounds__(256) void k_scatter(int n) {
    __shared__ int cols[P2CAP];
    __shared__ int cur[256];
    int b  = blockIdx.x;
    int v0 = b << NB_SHIFT;
    if (v0 >= n) return;
    int v1   = min(v0 + 256, n);
    int base = g_row[v0];
    int len  = g_row[v1] - base;
    int tid  = threadIdx.x;
    if (v0 + tid < v1) cur[tid] = g_row[v0 + tid] - base;
    __syncthreads();
    for (int i = tid; i < len; i += 256) {
        int2 pr  = g_stage[base + i];
        int  pos = atomicAdd(&cur[pr.x - v0], 1);
        if (pos < P2CAP) cols[pos] = pr.y;
        else             g_col[base + pos] = pr.y;
    }
    __syncthreads();
    int lim = len < P2CAP ? len : P2CAP;
    for (int i = tid; i < lim; i += 256) g_col[base + i] = cols[i];
}

// ---- fused input layer + conv1 HW: g_t16 = dis * (relu(x@Win+bin) @ W1) ----
// single 17.4 KB LDS tile reused for x-chunks then h -> ~2x occupancy
__global__ __launch_bounds__(256) void k_inhw(const float* __restrict__ x,
                                              const float* __restrict__ Win,
                                              const float* __restrict__ bin,
                                              const float* __restrict__ W1, int n) {
    __shared__ float sh[TN][XP];
    int tid = threadIdx.x;
    int fg  = tid & 15;
    int ng  = tid >> 4;
    int n0  = blockIdx.x * TN;

    float acc[4][4];
    #pragma unroll
    for (int i = 0; i < 4; ++i)
        #pragma unroll
        for (int j = 0; j < 4; ++j) acc[i][j] = 0.0f;

    for (int c = 0; c < DIN / 64; ++c) {
        int k0 = c * 64;
        __syncthreads();
        #pragma unroll
        for (int p = 0; p < 4; ++p) {
            int row = p * 16 + (tid >> 4);
            int col = (tid & 15) * 4;
            float4 v = make_float4(0.f, 0.f, 0.f, 0.f);
            if (n0 + row < n)
                v = *(const float4*)(x + (size_t)(n0 + row) * DIN + k0 + col);
            *(float4*)&sh[row][col] = v;
        }
        __syncthreads();
        #pragma unroll 16
        for (int k = 0; k < 64; ++k) {
            float4 w = *(const float4*)(Win + (size_t)(k0 + k) * HDIM + fg * 4);
            #pragma unroll
            for (int i = 0; i < 4; ++i) {
                float xv = sh[ng * 4 + i][k];
                acc[i][0] += xv * w.x; acc[i][1] += xv * w.y;
                acc[i][2] += xv * w.z; acc[i][3] += xv * w.w;
            }
        }
    }
    __syncthreads();              // all reads of x-tile done; reuse sh for h
    float4 bb = *(const float4*)(bin + fg * 4);
    #pragma unroll
    for (int i = 0; i < 4; ++i) {
        float4 hv;
        hv.x = fmaxf(acc[i][0] + bb.x, 0.f);
        hv.y = fmaxf(acc[i][1] + bb.y, 0.f);
        hv.z = fmaxf(acc[i][2] + bb.z, 0.f);
        hv.w = fmaxf(acc[i][3] + bb.w, 0.f);
        *(float4*)&sh[ng * 4 + i][fg * 4] = hv;
    }
    __syncthreads();
    float a2[4][4];
    #pragma unroll
    for (int i = 0; i < 4; ++i)
        #pragma unroll
        for (int j = 0; j < 4; ++j) a2[i][j] = 0.0f;
    #pragma unroll 16
    for (int k = 0; k < 64; ++k) {
        float4 w = *(const float4*)(W1 + (size_t)k * HDIM + fg * 4);
        #pragma unroll
        for (int i = 0; i < 4; ++i) {
            float hv = sh[ng * 4 + i][k];
            a2[i][0] += hv * w.x; a2[i][1] += hv * w.y;
            a2[i][2] += hv * w.z; a2[i][3] += hv * w.w;
        }
    }
    #pragma unroll
    for (int i = 0; i < 4; ++i) {
        int node = n0 + ng * 4 + i;
        if (node < n) {
            float dv = g_dis[node];
            union { __half2 h2[2]; float2 f2; } u;
            u.h2[0] = __floats2half2_rn(dv * a2[i][0], dv * a2[i][1]);
            u.h2[1] = __floats2half2_rn(dv * a2[i][2], dv * a2[i][3]);
            *(float2*)(g_t16 + (size_t)node * HDIM + fg * 4) = u.f2;
        }
    }
}

// ---- conv2 HW: g_t16 = dis * (g_h @ W2) ----
__global__ __launch_bounds__(256) void k_hw2(const float* __restrict__ W2, int n) {
    __shared__ float sh[TN][XP];
    int tid = threadIdx.x;
    int fg  = tid & 15;
    int ng  = tid >> 4;
    int n0  = blockIdx.x * TN;

    #pragma unroll
    for (int p = 0; p < 4; ++p) {
        int row = p * 16 + (tid >> 4);
        int col = (tid & 15) * 4;
        float4 v = make_float4(0.f, 0.f, 0.f, 0.f);
        if (n0 + row < n)
            v = *(const float4*)(g_h + (size_t)(n0 + row) * HDIM + col);
        *(float4*)&sh[row][col] = v;
    }
    __syncthreads();
    float acc[4][4];
    #pragma unroll
    for (int i = 0; i < 4; ++i)
        #pragma unroll
        for (int j = 0; j < 4; ++j) acc[i][j] = 0.0f;
    #pragma unroll 16
    for (int k = 0; k < 64; ++k) {
        float4 w = *(const float4*)(W2 + (size_t)k * HDIM + fg * 4);
        #pragma unroll
        for (int i = 0; i < 4; ++i) {
            float hv = sh[ng * 4 + i][k];
            acc[i][0] += hv * w.x; acc[i][1] += hv * w.y;
            acc[i][2] += hv * w.z; acc[i][3] += hv * w.w;
        }
    }
    #pragma unroll
    for (int i = 0; i < 4; ++i) {
        int node = n0 + ng * 4 + i;
        if (node < n) {
            float dv = g_dis[node];
            union { __half2 h2[2]; float2 f2; } u;
            u.h2[0] = __floats2half2_rn(dv * acc[i][0], dv * acc[i][1]);
            u.h2[1] = __floats2half2_rn(dv * acc[i][2], dv * acc[i][3]);
            *(float2*)(g_t16 + (size_t)node * HDIM + fg * 4) = u.f2;
        }
    }
}

// CSR gather over fp16 premultiplied messages:
// h_v = relu( dis_v * ( sum_{u in N(v)} t16_u + t16_v ) + b )
__global__ void k_gather(const float* __restrict__ b, int n) {
    int idx = blockIdx.x * blockDim.x + threadIdx.x;
    int v   = idx >> 6;
    int f   = idx & 63;
    if (v >= n) return;
    int beg = g_row[v], end = g_row[v + 1];
    float acc = __half2float(g_t16[(size_t)v * HDIM + f]);   // self term
    int j = beg;
    for (; j + 8 <= end; j += 8) {
        int u0 = g_col[j],     u1 = g_col[j + 1], u2 = g_col[j + 2], u3 = g_col[j + 3];
        int u4 = g_col[j + 4], u5 = g_col[j + 5], u6 = g_col[j + 6], u7 = g_col[j + 7];
        float s0 = __half2float(g_t16[(size_t)u0 * HDIM + f]);
        float s1 = __half2float(g_t16[(size_t)u1 * HDIM + f]);
        float s2 = __half2float(g_t16[(size_t)u2 * HDIM + f]);
        float s3 = __half2float(g_t16[(size_t)u3 * HDIM + f]);
        float s4 = __half2float(g_t16[(size_t)u4 * HDIM + f]);
        float s5 = __half2float(g_t16[(size_t)u5 * HDIM + f]);
        float s6 = __half2float(g_t16[(size_t)u6 * HDIM + f]);
        float s7 = __half2float(g_t16[(size_t)u7 * HDIM + f]);
        acc += ((s0 + s1) + (s2 + s3)) + ((s4 + s5) + (s6 + s7));
    }
    for (; j < end; ++j) {
        int u = g_col[j];
        acc += __half2float(g_t16[(size_t)u * HDIM + f]);
    }
    float dv = g_dis[v];
    g_h[(size_t)v * HDIM + f] = fmaxf(dv * acc + b[f], 0.0f);
}

// fused mean-pool + MLP head + log_softmax; 4 waves per graph
__global__ void k_poolhead(const float* __restrict__ Wf1, const float* __restrict__ bf1,
                           const float* __restrict__ Wf2, const float* __restrict__ bf2,
                           float* __restrict__ out) {
    __shared__ float ps[4][HDIM];
    __shared__ float p[HDIM];
    __shared__ float z[DOUTD];
    int g   = blockIdx.x;
    int tid = threadIdx.x;
    int f   = tid & 63, q = tid >> 6;
    int beg = g_gptr[g], end = g_gptr[g + 1];
    float s = 0.0f;
    for (int i = beg + q; i < end; i += 4)
        s += g_h[(size_t)i * HDIM + f];
    ps[q][f] = s;
    __syncthreads();
    if (tid < HDIM) {
        float cnt = fmaxf((float)(end - beg), 1.0f);
        p[tid] = (ps[0][tid] + ps[1][tid] + ps[2][tid] + ps[3][tid]) / cnt;
    }
    __syncthreads();
    if (tid < DOUTD) {
        float a = bf1[tid];
        for (int k = 0; k < HDIM; ++k)
            a += p[k] * Wf1[k * DOUTD + tid];
        z[tid] = fmaxf(a, 0.0f);
    }
    __syncthreads();
    if (tid == 0) {
        float l0 = bf2[0], l1 = bf2[1];
        for (int k = 0; k < DOUTD; ++k) {
            l0 += z[k] * Wf2[k * NCLS + 0];
            l1 += z[k] * Wf2[k * NCLS + 1];
        }
        float m   = fmaxf(l0, l1);
        float lse = m + logf(expf(l0 - m) + expf(l1 - m));
        out[g * NCLS + 0] = l0 - lse;
        out[g * NCLS + 1] = l1 - lse;
    }
}

extern "C" void kernel_launch(void* const* d_in, const int* in_sizes, int n_in,
                              void* d_out, int out_size, void* d_ws, size_t ws_size,
                              hipStream_t stream) {
    (void)d_ws; (void)ws_size; (void)out_size;

    const float* x   = (const float*)d_in[0];
    const int*   ei  = (const int*)d_in[1];
    const int*   bat = (const int*)d_in[2];

    const float* wp[10] = {nullptr};
    int wi = 0;
    for (int i = 3; i < n_in && wi < 10; ++i) {
        if (in_sizes[i] == 1) continue;
        wp[wi++] = (const float*)d_in[i];
    }
    const float* W_in = wp[0];
    const float* b_in = wp[1];
    const float* W1   = wp[2];
    const float* b1   = wp[3];
    const float* W2   = wp[4];
    const float* b2   = wp[5];
    const float* Wf1  = wp[6];
    const float* bf1  = wp[7];
    const float* Wf2  = wp[8];
    const float* bf2  = wp[9];

    const int n = in_sizes[0] / DIN;
    const int E = in_sizes[1] / 2;

    const int B = 256;
    int gE     = (E + B - 1) / B;
    int gE2    = (2 * E + B - 1) / B;
    int gN     = (n + B - 1) / B;
    int gN1    = (n + 1 + B - 1) / B;
    int gNH    = (int)(((long long)n * HDIM + B - 1) / B);
    int nb     = (n + SCAN_B - 1) / SCAN_B;
    int gTile  = (n + TN - 1) / TN;
    int gStage = (E + T1E - 1) / T1E;
    int gBk    = (NBUCK + B - 1) / B;

    k_prep<<<gN, B, 0, stream>>>(n);
    k_detect<<<gE, B, 0, stream>>>(ei, E);
    k_setflag<<<1, 1, 0, stream>>>();
    k_deghist<<<gE2, B, 0, stream>>>(ei, 2 * E);
    k_dis<<<gN, B, 0, stream>>>(n);
    k_gptr<<<gN1, B, 0, stream>>>(bat, n);

    k_scan1<<<nb, SCAN_B, 0, stream>>>(n);
    k_scan2<<<1, 1, 0, stream>>>(nb);
    k_scan3<<<nb, SCAN_B, 0, stream>>>(n);
    k_binit<<<gBk, B, 0, stream>>>(n);
    k_stage<<<gStage, 256, 0, stream>>>(ei, E);
    k_scatter<<<NBUCK, 256, 0, stream>>>(n);

    // fused input layer + conv1 HW
    k_inhw<<<gTile, 256, 0, stream>>>(x, W_in, b_in, W1, n);
    k_gather<<<gNH, B, 0, stream>>>(b1, n);

    // conv 2
    k_hw2<<<gTile, 256, 0, stream>>>(W2, n);
    k_gather<<<gNH, B, 0, stream>>>(b2, n);

    k_poolhead<<<NGRAPH, 256, 0, stream>>>(Wf1, bf1, Wf2, bf2, (float*)d_out);
}